// Round 9
// baseline (207.669 us; speedup 1.0000x reference)
//
#include <hip/hip_runtime.h>

#define CIN 256
#define CB 64
#define KNB 27

typedef __attribute__((ext_vector_type(8))) short short8_t;   // 8 x bf16
typedef __attribute__((ext_vector_type(4))) float f32x4;
typedef __attribute__((ext_vector_type(4))) int   i32x4;

__device__ inline unsigned short f2bf(float f) {
    union { float f; unsigned u; } x; x.f = f;
    unsigned r = x.u + 0x7fffu + ((x.u >> 16) & 1u);   // RNE
    return (unsigned short)(r >> 16);
}
__device__ inline float bf2f(unsigned short h) {
    union { unsigned u; float f; } x; x.u = ((unsigned)h) << 16; return x.f;
}
__device__ inline f32x4 mfma16(short8_t a, short8_t b, f32x4 c) {
    return __builtin_amdgcn_mfma_f32_16x16x32_bf16(a, b, c, 0, 0, 0);
}
__device__ inline i32x4 mfma_i8(i32x4 a, i32x4 b, i32x4 c) {
    return __builtin_amdgcn_mfma_i32_16x16x64_i8(a, b, c, 0, 0, 0);
}

// ---------------------------------------------------------------------------
// prep_a: w1p/w2p bf16 frag-packed + biases (no atomics, no reductions)
// frag layout (bf16): flat = ((kstep*T + tile)*64 + lane)*8 + j
// ---------------------------------------------------------------------------
__global__ __launch_bounds__(256) void prep_a_kernel(
    const float* __restrict__ w1, const float* __restrict__ w2,
    const float* __restrict__ g1, const float* __restrict__ b1, const float* __restrict__ m1, const float* __restrict__ v1,
    const float* __restrict__ g2, const float* __restrict__ b2, const float* __restrict__ m2, const float* __restrict__ v2,
    const float* __restrict__ g3, const float* __restrict__ b3, const float* __restrict__ m3, const float* __restrict__ v3,
    unsigned short* __restrict__ w1p, unsigned short* __restrict__ w2p,
    float* __restrict__ bias1, float* __restrict__ bias2, float* __restrict__ bias3)
{
    int t = blockIdx.x * 256 + threadIdx.x;
    if (t < 16384) {                          // w1p: [s:8][t:4][lane:64][j:8]
        int j = t & 7, lane = (t >> 3) & 63, tt = (t >> 9) & 3, s = t >> 11;
        int c = s * 32 + (lane >> 4) * 8 + j;
        int d = tt * 16 + (lane & 15);
        float sc = g1[d] * rsqrtf(v1[d] + 1e-5f);
        w1p[t] = f2bf(w1[c * CB + d] * sc);
    } else if (t < 32768) {                   // w2p: [s:2][mt:16][lane:64][j:8]
        int u = t - 16384;
        int j = u & 7, lane = (u >> 3) & 63, mt = (u >> 9) & 15, s = u >> 13;
        int c = s * 32 + (lane >> 4) * 8 + j;
        int d = mt * 16 + (lane & 15);
        float sc = g3[d] * rsqrtf(v3[d] + 1e-5f);
        w2p[u] = f2bf(w2[c * CIN + d] * sc);
    } else if (t < 33152) {
        int u = t - 32768;
        if (u < 64)       { float sc = g1[u] * rsqrtf(v1[u] + 1e-5f); bias1[u] = b1[u] - m1[u] * sc; }
        else if (u < 128) { int d = u - 64;  float sc = g2[d] * rsqrtf(v2[d] + 1e-5f); bias2[d] = b2[d] - m2[d] * sc; }
        else              { int d = u - 128; float sc = g3[d] * rsqrtf(v3[d] + 1e-5f); bias3[d] = b3[d] - m3[d] * sc; }
    }
}

// ---------------------------------------------------------------------------
// prep_bq: each block independently computes the GLOBAL max of BN-folded w3
// (redundant, parallel, no atomics), then quantizes its own 256-element
// slice to int8 packed for mfma_i32_16x16x64_i8:
// byte flat = ((k*4 + tile)*64 + lane)*16 + j ; c=(lane>>4)*16+j, d=tile*16+(lane&15)
// Block 0 thread 0 stores amax[1] (plain store, deterministic).
// ---------------------------------------------------------------------------
__global__ __launch_bounds__(256) void prep_bq_kernel(
    const float* __restrict__ w3, const float* __restrict__ g2, const float* __restrict__ v2,
    signed char* __restrict__ w3q, unsigned* __restrict__ amax)
{
    __shared__ float sc2[64];
    __shared__ float sm[4];
    int tid = threadIdx.x;
    if (tid < 64) sc2[tid] = g2[tid] * rsqrtf(v2[tid] + 1e-5f);
    __syncthreads();

    const float4* w34 = (const float4*)w3;
    float m = 0.f;
    for (int e = tid; e < KNB * CB * CB / 4; e += 256) {
        float4 v = w34[e];
        int d0 = (e * 4) & 63;
        m = fmaxf(m, fabsf(v.x * sc2[d0]));
        m = fmaxf(m, fabsf(v.y * sc2[d0 + 1]));
        m = fmaxf(m, fabsf(v.z * sc2[d0 + 2]));
        m = fmaxf(m, fabsf(v.w * sc2[d0 + 3]));
    }
#pragma unroll
    for (int off = 32; off; off >>= 1) m = fmaxf(m, __shfl_xor(m, off));
    if ((tid & 63) == 0) sm[tid >> 6] = m;
    __syncthreads();
    float mm = fmaxf(fmaxf(sm[0], sm[1]), fmaxf(sm[2], sm[3]));
    float inv = mm > 0.f ? 127.f / mm : 0.f;

    int u = blockIdx.x * 256 + tid;           // 0..110591
    int j = u & 15, lane = (u >> 4) & 63, tile = (u >> 10) & 3, k = u >> 12;
    int c = (lane >> 4) * 16 + j;
    int d = tile * 16 + (lane & 15);
    int q = __float2int_rn(w3[(k * CB + c) * CB + d] * sc2[d] * inv);
    q = q > 127 ? 127 : (q < -127 ? -127 : q);
    w3q[u] = (signed char)q;
    if (blockIdx.x == 0 && tid == 0) amax[1] = __float_as_uint(mm);
}

// ---------------------------------------------------------------------------
// k1: c1 = relu(data @ w1' + bias1) -> bf16 [N,64]; block max -> blockmax[bid]
// ---------------------------------------------------------------------------
__global__ __launch_bounds__(256) void k1_conv1x1a(
    const float* __restrict__ data, const unsigned short* __restrict__ w1p,
    const float* __restrict__ bias1, unsigned short* __restrict__ c1b,
    float* __restrict__ blockmax)
{
    __shared__ short8_t w1s[2048];   // 32 KB
    __shared__ float smax[4];
    int tid = threadIdx.x;
    const short8_t* wsrc = (const short8_t*)w1p;
#pragma unroll
    for (int i = 0; i < 8; i++) w1s[tid + i * 256] = wsrc[tid + i * 256];

    int lane = tid & 63, wave = tid >> 6;
    int g = lane >> 4, r = lane & 15;
    int rowbase = blockIdx.x * 128 + wave * 32;
    f32x4 acc[2][4] = {};
    __syncthreads();

#pragma unroll
    for (int s = 0; s < 8; s++) {
        short8_t a[2];
#pragma unroll
        for (int sub = 0; sub < 2; sub++) {
            const float* ap = data + (size_t)(rowbase + sub * 16 + r) * CIN + s * 32 + g * 8;
            float4 f0 = *(const float4*)ap;
            float4 f1 = *(const float4*)(ap + 4);
            short8_t av;
            av[0] = (short)f2bf(f0.x); av[1] = (short)f2bf(f0.y);
            av[2] = (short)f2bf(f0.z); av[3] = (short)f2bf(f0.w);
            av[4] = (short)f2bf(f1.x); av[5] = (short)f2bf(f1.y);
            av[6] = (short)f2bf(f1.z); av[7] = (short)f2bf(f1.w);
            a[sub] = av;
        }
#pragma unroll
        for (int t = 0; t < 4; t++) {
            short8_t b = w1s[(s * 4 + t) * 64 + lane];
            acc[0][t] = mfma16(a[0], b, acc[0][t]);
            acc[1][t] = mfma16(a[1], b, acc[1][t]);
        }
    }

    float mloc = 0.f;
#pragma unroll
    for (int sub = 0; sub < 2; sub++)
#pragma unroll
        for (int t = 0; t < 4; t++) {
            int col = t * 16 + r;
            float bs = bias1[col];
#pragma unroll
            for (int i = 0; i < 4; i++) {
                int row = rowbase + sub * 16 + g * 4 + i;
                float v = fmaxf(acc[sub][t][i] + bs, 0.f);
                mloc = fmaxf(mloc, v);
                c1b[row * CB + col] = f2bf(v);
            }
        }
#pragma unroll
    for (int off = 32; off; off >>= 1) mloc = fmaxf(mloc, __shfl_xor(mloc, off));
    if (lane == 0) smax[wave] = mloc;
    __syncthreads();
    if (tid == 0)
        blockmax[blockIdx.x] = fmaxf(fmaxf(smax[0], smax[1]), fmaxf(smax[2], smax[3]));
}

// ---------------------------------------------------------------------------
// quant_c1: each block re-reduces blockmax[1024] (one float4/thread) ->
// global c1 max, then quantizes its 16B slice. Block 0 stores amax[0].
// ---------------------------------------------------------------------------
__global__ __launch_bounds__(256) void quant_c1_kernel(
    const unsigned short* __restrict__ c1b, const float* __restrict__ blockmax,
    signed char* __restrict__ c1q, unsigned* __restrict__ amax)
{
    __shared__ float sm[4];
    int tid = threadIdx.x;
    float4 bm = ((const float4*)blockmax)[tid];
    float m = fmaxf(fmaxf(bm.x, bm.y), fmaxf(bm.z, bm.w));
#pragma unroll
    for (int off = 32; off; off >>= 1) m = fmaxf(m, __shfl_xor(m, off));
    if ((tid & 63) == 0) sm[tid >> 6] = m;
    __syncthreads();
    float s1 = fmaxf(fmaxf(sm[0], sm[1]), fmaxf(sm[2], sm[3]));
    float inv = s1 > 0.f ? 127.f / s1 : 0.f;

    int t = blockIdx.x * 256 + tid;           // 16-byte unit, 524288 total
    const short8_t* src = (const short8_t*)c1b;
    short8_t v0 = src[t * 2], v1 = src[t * 2 + 1];
    int ow[4];
#pragma unroll
    for (int h = 0; h < 4; h++) {
        int w = 0;
#pragma unroll
        for (int e = 0; e < 4; e++) {
            unsigned short hv = (unsigned short)((h < 2 ? v0 : v1)[(h & 1) * 4 + e]);
            int q = __float2int_rn(bf2f(hv) * inv);
            q = q > 127 ? 127 : q;             // c1 >= 0
            w |= (q & 0xff) << (e * 8);
        }
        ow[h] = w;
    }
    ((int4*)c1q)[t] = make_int4(ow[0], ow[1], ow[2], ow[3]);
    if (blockIdx.x == 0 && tid == 0) amax[0] = __float_as_uint(s1);
}

// ---------------------------------------------------------------------------
// k2 v7: int8 gather (64 B/row) + mfma_i32_16x16x64_i8, i32 accumulate.
// 2-WAVE blocks (128 threads, 64 rows): halves workgroup count per CU so the
// per-CU workgroup-slot limit allows ~2x the resident waves vs 1-wave blocks.
// ---------------------------------------------------------------------------
__global__ __launch_bounds__(128, 6) void k2_conv3x3(
    const signed char* __restrict__ c1q, const int* __restrict__ neigh,
    const signed char* __restrict__ w3q, const float* __restrict__ bias2,
    const unsigned* __restrict__ amax, unsigned short* __restrict__ c2b)
{
    __shared__ int nidx[64 * KNB];           // 6912 B
    int tid = threadIdx.x;
    int rowbase = blockIdx.x * 64;

    // coalesced cooperative load of this block's neighbor table (1728 ints)
    const int4* nsrc = (const int4*)(neigh + (size_t)rowbase * KNB);
#pragma unroll
    for (int i = 0; i < 4; i++) {
        int p = tid + i * 128;
        if (p < 432) ((int4*)nidx)[p] = nsrc[p];
    }

    int lane = tid & 63, wave = tid >> 6;
    int g = lane >> 4, r = lane & 15;
    int lr0 = wave * 32 + r, lr1 = wave * 32 + 16 + r;
    float sf = __uint_as_float(amax[0]) * __uint_as_float(amax[1]) * (1.f / (127.f * 127.f));
    __syncthreads();

    const i32x4* bq = (const i32x4*)w3q;     // [k][tile:4][lane:64] x 16B
    i32x4 iacc[2][4] = {};

#pragma unroll
    for (int k = 0; k < KNB; k++) {
        i32x4 b0 = bq[k * 256 + lane];
        i32x4 b1 = bq[k * 256 + 64 + lane];
        i32x4 b2 = bq[k * 256 + 128 + lane];
        i32x4 b3 = bq[k * 256 + 192 + lane];
        int i0 = nidx[lr0 * KNB + k];
        int i1 = nidx[lr1 * KNB + k];
        i32x4 a0 = *(const i32x4*)(c1q + (size_t)i0 * CB + g * 16);
        i32x4 a1 = *(const i32x4*)(c1q + (size_t)i1 * CB + g * 16);
        iacc[0][0] = mfma_i8(a0, b0, iacc[0][0]);
        iacc[1][0] = mfma_i8(a1, b0, iacc[1][0]);
        iacc[0][1] = mfma_i8(a0, b1, iacc[0][1]);
        iacc[1][1] = mfma_i8(a1, b1, iacc[1][1]);
        iacc[0][2] = mfma_i8(a0, b2, iacc[0][2]);
        iacc[1][2] = mfma_i8(a1, b2, iacc[1][2]);
        iacc[0][3] = mfma_i8(a0, b3, iacc[0][3]);
        iacc[1][3] = mfma_i8(a1, b3, iacc[1][3]);
    }

#pragma unroll
    for (int sub = 0; sub < 2; sub++)
#pragma unroll
        for (int t = 0; t < 4; t++) {
            int col = t * 16 + r;
            float bs = bias2[col];
#pragma unroll
            for (int i = 0; i < 4; i++) {
                int row = rowbase + wave * 32 + sub * 16 + g * 4 + i;
                float v = fmaxf((float)iacc[sub][t][i] * sf + bs, 0.f);
                c2b[row * CB + col] = f2bf(v);
            }
        }
}

// ---------------------------------------------------------------------------
// k3 v3: out = relu(c2 @ w2' + bias3 + data), fp32 [N,256]
// Transposed GEMM, 64 rows/block (A-frags reused 4x), float4 residual RMW.
// ---------------------------------------------------------------------------
__global__ __launch_bounds__(256) void k3_conv1x1b(
    const unsigned short* __restrict__ c2b, const unsigned short* __restrict__ w2p,
    const float* __restrict__ bias3, const float* __restrict__ data,
    float* __restrict__ out)
{
    int tid = threadIdx.x;
    int lane = tid & 63, wave = tid >> 6;
    int g = lane >> 4, r = lane & 15;
    int rowbase = blockIdx.x * 64;

    const short8_t* abase = (const short8_t*)w2p;
    short8_t bfr[4][2];
#pragma unroll
    for (int sub = 0; sub < 4; sub++)
#pragma unroll
        for (int s = 0; s < 2; s++)
            bfr[sub][s] = *(const short8_t*)(c2b + (size_t)(rowbase + sub * 16 + r) * CB + s * 32 + g * 8);

    f32x4 acc2[4][4] = {};
#pragma unroll
    for (int s = 0; s < 2; s++)
#pragma unroll
        for (int mt = 0; mt < 4; mt++) {
            short8_t a = abase[(s * 16 + wave * 4 + mt) * 64 + lane];
#pragma unroll
            for (int sub = 0; sub < 4; sub++)
                acc2[sub][mt] = mfma16(a, bfr[sub][s], acc2[sub][mt]);
        }

#pragma unroll
    for (int sub = 0; sub < 4; sub++)
#pragma unroll
        for (int mt = 0; mt < 4; mt++) {
            int col0 = (wave * 4 + mt) * 16 + g * 4;
            int rowg = rowbase + sub * 16 + r;
            float4 bs = *(const float4*)(bias3 + col0);
            float4 dv = *(const float4*)(data + (size_t)rowg * CIN + col0);
            f32x4 v = acc2[sub][mt];
            float4 res;
            res.x = fmaxf(v[0] + bs.x + dv.x, 0.f);
            res.y = fmaxf(v[1] + bs.y + dv.y, 0.f);
            res.z = fmaxf(v[2] + bs.z + dv.z, 0.f);
            res.w = fmaxf(v[3] + bs.w + dv.w, 0.f);
            *(float4*)(out + (size_t)rowg * CIN + col0) = res;
        }
}

extern "C" void kernel_launch(void* const* d_in, const int* in_sizes, int n_in,
                              void* d_out, int out_size, void* d_ws, size_t ws_size,
                              hipStream_t stream)
{
    const float* data = (const float*)d_in[0];
    const int* neigh  = (const int*)d_in[1];
    const float* w1 = (const float*)d_in[3];
    const float* g1 = (const float*)d_in[4];
    const float* b1 = (const float*)d_in[5];
    const float* m1 = (const float*)d_in[6];
    const float* v1 = (const float*)d_in[7];
    const float* w3 = (const float*)d_in[8];
    const float* g2 = (const float*)d_in[9];
    const float* b2 = (const float*)d_in[10];
    const float* m2 = (const float*)d_in[11];
    const float* v2 = (const float*)d_in[12];
    const float* w2 = (const float*)d_in[13];
    const float* g3 = (const float*)d_in[14];
    const float* b3 = (const float*)d_in[15];
    const float* m3 = (const float*)d_in[16];
    const float* v3 = (const float*)d_in[17];
    float* out = (float*)d_out;

    char* ws = (char*)d_ws;
    // ws layout (~25.4 MB)
    unsigned short* c1b = (unsigned short*)ws;                      // 16 MB
    unsigned short* c2b = (unsigned short*)ws;                      // alias (c1b dead after quant)
    signed char*    c1q = (signed char*)(ws + 16777216);            // 8 MB
    unsigned short* w1p = (unsigned short*)(ws + 25165824);         // 32 KB
    signed char*    w3q = (signed char*)(ws + 25198592);            // 108 KB
    unsigned short* w2p = (unsigned short*)(ws + 25309184);         // 32 KB
    float* bias1 = (float*)(ws + 25341952);
    float* bias2 = bias1 + 64;
    float* bias3 = bias1 + 128;
    unsigned* amax = (unsigned*)(ws + 25343488);                    // 16 B
    float* blockmax = (float*)(ws + 25343552);                      // 4 KB

    int n = in_sizes[0] / CIN;   // 131072

    hipLaunchKernelGGL(prep_a_kernel, dim3(130), dim3(256), 0, stream,
                       w1, w2, g1, b1, m1, v1, g2, b2, m2, v2, g3, b3, m3, v3,
                       w1p, w2p, bias1, bias2, bias3);
    hipLaunchKernelGGL(prep_bq_kernel, dim3(432), dim3(256), 0, stream,
                       w3, g2, v2, w3q, amax);
    hipLaunchKernelGGL(k1_conv1x1a, dim3(n / 128), dim3(256), 0, stream,
                       data, w1p, bias1, c1b, blockmax);
    hipLaunchKernelGGL(quant_c1_kernel, dim3(2048), dim3(256), 0, stream,
                       c1b, blockmax, c1q, amax);
    hipLaunchKernelGGL(k2_conv3x3, dim3(n / 64), dim3(128), 0, stream,
                       c1q, neigh, w3q, bias2, amax, c2b);
    hipLaunchKernelGGL(k3_conv1x1b, dim3(n / 64), dim3(256), 0, stream,
                       c2b, w2p, bias3, data, out);
}

// Round 10
// 167.010 us; speedup vs baseline: 1.2434x; 1.2434x over previous
//
#include <hip/hip_runtime.h>

#define CIN 256
#define CB 64
#define KNB 27

typedef __attribute__((ext_vector_type(8))) short short8_t;   // 8 x bf16
typedef __attribute__((ext_vector_type(4))) float f32x4;
typedef __attribute__((ext_vector_type(4))) int   i32x4;

__device__ inline unsigned short f2bf(float f) {
    union { float f; unsigned u; } x; x.f = f;
    unsigned r = x.u + 0x7fffu + ((x.u >> 16) & 1u);   // RNE
    return (unsigned short)(r >> 16);
}
__device__ inline float bf2f(unsigned short h) {
    union { unsigned u; float f; } x; x.u = ((unsigned)h) << 16; return x.f;
}
__device__ inline f32x4 mfma16(short8_t a, short8_t b, f32x4 c) {
    return __builtin_amdgcn_mfma_f32_16x16x32_bf16(a, b, c, 0, 0, 0);
}
__device__ inline i32x4 mfma_i8(i32x4 a, i32x4 b, i32x4 c) {
    return __builtin_amdgcn_mfma_i32_16x16x64_i8(a, b, c, 0, 0, 0);
}

// ---------------------------------------------------------------------------
// prep_a: w1p/w2p bf16 frag-packed + biases (no atomics, no reductions)
// frag layout (bf16): flat = ((kstep*T + tile)*64 + lane)*8 + j
// ---------------------------------------------------------------------------
__global__ __launch_bounds__(256) void prep_a_kernel(
    const float* __restrict__ w1, const float* __restrict__ w2,
    const float* __restrict__ g1, const float* __restrict__ b1, const float* __restrict__ m1, const float* __restrict__ v1,
    const float* __restrict__ g2, const float* __restrict__ b2, const float* __restrict__ m2, const float* __restrict__ v2,
    const float* __restrict__ g3, const float* __restrict__ b3, const float* __restrict__ m3, const float* __restrict__ v3,
    unsigned short* __restrict__ w1p, unsigned short* __restrict__ w2p,
    float* __restrict__ bias1, float* __restrict__ bias2, float* __restrict__ bias3)
{
    int t = blockIdx.x * 256 + threadIdx.x;
    if (t < 16384) {                          // w1p: [s:8][t:4][lane:64][j:8]
        int j = t & 7, lane = (t >> 3) & 63, tt = (t >> 9) & 3, s = t >> 11;
        int c = s * 32 + (lane >> 4) * 8 + j;
        int d = tt * 16 + (lane & 15);
        float sc = g1[d] * rsqrtf(v1[d] + 1e-5f);
        w1p[t] = f2bf(w1[c * CB + d] * sc);
    } else if (t < 32768) {                   // w2p: [s:2][mt:16][lane:64][j:8]
        int u = t - 16384;
        int j = u & 7, lane = (u >> 3) & 63, mt = (u >> 9) & 15, s = u >> 13;
        int c = s * 32 + (lane >> 4) * 8 + j;
        int d = mt * 16 + (lane & 15);
        float sc = g3[d] * rsqrtf(v3[d] + 1e-5f);
        w2p[u] = f2bf(w2[c * CIN + d] * sc);
    } else if (t < 33152) {
        int u = t - 32768;
        if (u < 64)       { float sc = g1[u] * rsqrtf(v1[u] + 1e-5f); bias1[u] = b1[u] - m1[u] * sc; }
        else if (u < 128) { int d = u - 64;  float sc = g2[d] * rsqrtf(v2[d] + 1e-5f); bias2[d] = b2[d] - m2[d] * sc; }
        else              { int d = u - 128; float sc = g3[d] * rsqrtf(v3[d] + 1e-5f); bias3[d] = b3[d] - m3[d] * sc; }
    }
}

// ---------------------------------------------------------------------------
// prep_bq: each block independently computes the GLOBAL max of BN-folded w3
// (redundant, parallel, no atomics), then quantizes its own 256-element
// slice to int8 packed for mfma_i32_16x16x64_i8:
// byte flat = ((k*4 + tile)*64 + lane)*16 + j ; c=(lane>>4)*16+j, d=tile*16+(lane&15)
// Block 0 thread 0 stores amax[1] (plain store, deterministic).
// ---------------------------------------------------------------------------
__global__ __launch_bounds__(256) void prep_bq_kernel(
    const float* __restrict__ w3, const float* __restrict__ g2, const float* __restrict__ v2,
    signed char* __restrict__ w3q, unsigned* __restrict__ amax)
{
    __shared__ float sc2[64];
    __shared__ float sm[4];
    int tid = threadIdx.x;
    if (tid < 64) sc2[tid] = g2[tid] * rsqrtf(v2[tid] + 1e-5f);
    __syncthreads();

    const float4* w34 = (const float4*)w3;
    float m = 0.f;
    for (int e = tid; e < KNB * CB * CB / 4; e += 256) {
        float4 v = w34[e];
        int d0 = (e * 4) & 63;
        m = fmaxf(m, fabsf(v.x * sc2[d0]));
        m = fmaxf(m, fabsf(v.y * sc2[d0 + 1]));
        m = fmaxf(m, fabsf(v.z * sc2[d0 + 2]));
        m = fmaxf(m, fabsf(v.w * sc2[d0 + 3]));
    }
#pragma unroll
    for (int off = 32; off; off >>= 1) m = fmaxf(m, __shfl_xor(m, off));
    if ((tid & 63) == 0) sm[tid >> 6] = m;
    __syncthreads();
    float mm = fmaxf(fmaxf(sm[0], sm[1]), fmaxf(sm[2], sm[3]));
    float inv = mm > 0.f ? 127.f / mm : 0.f;

    int u = blockIdx.x * 256 + tid;           // 0..110591
    int j = u & 15, lane = (u >> 4) & 63, tile = (u >> 10) & 3, k = u >> 12;
    int c = (lane >> 4) * 16 + j;
    int d = tile * 16 + (lane & 15);
    int q = __float2int_rn(w3[(k * CB + c) * CB + d] * sc2[d] * inv);
    q = q > 127 ? 127 : (q < -127 ? -127 : q);
    w3q[u] = (signed char)q;
    if (blockIdx.x == 0 && tid == 0) amax[1] = __float_as_uint(mm);
}

// ---------------------------------------------------------------------------
// k1: c1 = relu(data @ w1' + bias1) -> bf16 [N,64]; block max -> blockmax[bid]
// ---------------------------------------------------------------------------
__global__ __launch_bounds__(256) void k1_conv1x1a(
    const float* __restrict__ data, const unsigned short* __restrict__ w1p,
    const float* __restrict__ bias1, unsigned short* __restrict__ c1b,
    float* __restrict__ blockmax)
{
    __shared__ short8_t w1s[2048];   // 32 KB
    __shared__ float smax[4];
    int tid = threadIdx.x;
    const short8_t* wsrc = (const short8_t*)w1p;
#pragma unroll
    for (int i = 0; i < 8; i++) w1s[tid + i * 256] = wsrc[tid + i * 256];

    int lane = tid & 63, wave = tid >> 6;
    int g = lane >> 4, r = lane & 15;
    int rowbase = blockIdx.x * 128 + wave * 32;
    f32x4 acc[2][4] = {};
    __syncthreads();

#pragma unroll
    for (int s = 0; s < 8; s++) {
        short8_t a[2];
#pragma unroll
        for (int sub = 0; sub < 2; sub++) {
            const float* ap = data + (size_t)(rowbase + sub * 16 + r) * CIN + s * 32 + g * 8;
            float4 f0 = *(const float4*)ap;
            float4 f1 = *(const float4*)(ap + 4);
            short8_t av;
            av[0] = (short)f2bf(f0.x); av[1] = (short)f2bf(f0.y);
            av[2] = (short)f2bf(f0.z); av[3] = (short)f2bf(f0.w);
            av[4] = (short)f2bf(f1.x); av[5] = (short)f2bf(f1.y);
            av[6] = (short)f2bf(f1.z); av[7] = (short)f2bf(f1.w);
            a[sub] = av;
        }
#pragma unroll
        for (int t = 0; t < 4; t++) {
            short8_t b = w1s[(s * 4 + t) * 64 + lane];
            acc[0][t] = mfma16(a[0], b, acc[0][t]);
            acc[1][t] = mfma16(a[1], b, acc[1][t]);
        }
    }

    float mloc = 0.f;
#pragma unroll
    for (int sub = 0; sub < 2; sub++)
#pragma unroll
        for (int t = 0; t < 4; t++) {
            int col = t * 16 + r;
            float bs = bias1[col];
#pragma unroll
            for (int i = 0; i < 4; i++) {
                int row = rowbase + sub * 16 + g * 4 + i;
                float v = fmaxf(acc[sub][t][i] + bs, 0.f);
                mloc = fmaxf(mloc, v);
                c1b[row * CB + col] = f2bf(v);
            }
        }
#pragma unroll
    for (int off = 32; off; off >>= 1) mloc = fmaxf(mloc, __shfl_xor(mloc, off));
    if (lane == 0) smax[wave] = mloc;
    __syncthreads();
    if (tid == 0)
        blockmax[blockIdx.x] = fmaxf(fmaxf(smax[0], smax[1]), fmaxf(smax[2], smax[3]));
}

// ---------------------------------------------------------------------------
// quant_c1: each block re-reduces blockmax[1024] (one float4/thread) ->
// global c1 max, then quantizes its 16B slice. Block 0 stores amax[0].
// ---------------------------------------------------------------------------
__global__ __launch_bounds__(256) void quant_c1_kernel(
    const unsigned short* __restrict__ c1b, const float* __restrict__ blockmax,
    signed char* __restrict__ c1q, unsigned* __restrict__ amax)
{
    __shared__ float sm[4];
    int tid = threadIdx.x;
    float4 bm = ((const float4*)blockmax)[tid];
    float m = fmaxf(fmaxf(bm.x, bm.y), fmaxf(bm.z, bm.w));
#pragma unroll
    for (int off = 32; off; off >>= 1) m = fmaxf(m, __shfl_xor(m, off));
    if ((tid & 63) == 0) sm[tid >> 6] = m;
    __syncthreads();
    float s1 = fmaxf(fmaxf(sm[0], sm[1]), fmaxf(sm[2], sm[3]));
    float inv = s1 > 0.f ? 127.f / s1 : 0.f;

    int t = blockIdx.x * 256 + tid;           // 16-byte unit, 524288 total
    const short8_t* src = (const short8_t*)c1b;
    short8_t v0 = src[t * 2], v1 = src[t * 2 + 1];
    int ow[4];
#pragma unroll
    for (int h = 0; h < 4; h++) {
        int w = 0;
#pragma unroll
        for (int e = 0; e < 4; e++) {
            unsigned short hv = (unsigned short)((h < 2 ? v0 : v1)[(h & 1) * 4 + e]);
            int q = __float2int_rn(bf2f(hv) * inv);
            q = q > 127 ? 127 : q;             // c1 >= 0
            w |= (q & 0xff) << (e * 8);
        }
        ow[h] = w;
    }
    ((int4*)c1q)[t] = make_int4(ow[0], ow[1], ow[2], ow[3]);
    if (blockIdx.x == 0 && tid == 0) amax[0] = __float_as_uint(s1);
}

// ---------------------------------------------------------------------------
// k2 (R7-best revert): int8 gather (64 B/row) + mfma_i32_16x16x64_i8,
// single-wave blocks (64 threads, 32 rows), 4096 blocks.
// ---------------------------------------------------------------------------
__global__ __launch_bounds__(64, 4) void k2_conv3x3(
    const signed char* __restrict__ c1q, const int* __restrict__ neigh,
    const signed char* __restrict__ w3q, const float* __restrict__ bias2,
    const unsigned* __restrict__ amax, unsigned short* __restrict__ c2b)
{
    __shared__ int nidx[32 * KNB];           // 3456 B
    int tid = threadIdx.x;
    int rowbase = blockIdx.x * 32;

    const int4* nsrc = (const int4*)(neigh + (size_t)rowbase * KNB);
#pragma unroll
    for (int i = 0; i < 4; i++) {
        int p = tid + i * 64;
        if (p < 216) ((int4*)nidx)[p] = nsrc[p];
    }

    int lane = tid;
    int g = lane >> 4, r = lane & 15;
    float sf = __uint_as_float(amax[0]) * __uint_as_float(amax[1]) * (1.f / (127.f * 127.f));
    __syncthreads();

    const i32x4* bq = (const i32x4*)w3q;     // [k][tile:4][lane:64] x 16B
    i32x4 iacc[2][4] = {};

#pragma unroll
    for (int k = 0; k < KNB; k++) {
        i32x4 b0 = bq[k * 256 + lane];
        i32x4 b1 = bq[k * 256 + 64 + lane];
        i32x4 b2 = bq[k * 256 + 128 + lane];
        i32x4 b3 = bq[k * 256 + 192 + lane];
        int i0 = nidx[r * KNB + k];
        int i1 = nidx[(16 + r) * KNB + k];
        i32x4 a0 = *(const i32x4*)(c1q + (size_t)i0 * CB + g * 16);
        i32x4 a1 = *(const i32x4*)(c1q + (size_t)i1 * CB + g * 16);
        iacc[0][0] = mfma_i8(a0, b0, iacc[0][0]);
        iacc[1][0] = mfma_i8(a1, b0, iacc[1][0]);
        iacc[0][1] = mfma_i8(a0, b1, iacc[0][1]);
        iacc[1][1] = mfma_i8(a1, b1, iacc[1][1]);
        iacc[0][2] = mfma_i8(a0, b2, iacc[0][2]);
        iacc[1][2] = mfma_i8(a1, b2, iacc[1][2]);
        iacc[0][3] = mfma_i8(a0, b3, iacc[0][3]);
        iacc[1][3] = mfma_i8(a1, b3, iacc[1][3]);
    }

#pragma unroll
    for (int sub = 0; sub < 2; sub++)
#pragma unroll
        for (int t = 0; t < 4; t++) {
            int col = t * 16 + r;
            float bs = bias2[col];
#pragma unroll
            for (int i = 0; i < 4; i++) {
                int row = rowbase + sub * 16 + g * 4 + i;
                float v = fmaxf((float)iacc[sub][t][i] * sf + bs, 0.f);
                c2b[row * CB + col] = f2bf(v);
            }
        }
}

// ---------------------------------------------------------------------------
// k3 v4: out = relu(c2 @ w2' + bias3 + data), fp32 [N,256]
// Transposed GEMM (A=w2 frags, B=c2 frags) -> +bias in reg -> LDS tile
// (stride 260, <=2-way banks) -> barrier -> fully-coalesced float4 pass:
// data load + residual + relu + out store at 1 KB/instruction.
// ---------------------------------------------------------------------------
__global__ __launch_bounds__(256) void k3_conv1x1b(
    const unsigned short* __restrict__ c2b, const unsigned short* __restrict__ w2p,
    const float* __restrict__ bias3, const float* __restrict__ data,
    float* __restrict__ out)
{
    __shared__ float otile[64 * 260];        // 66560 B -> 2 blocks/CU
    int tid = threadIdx.x;
    int lane = tid & 63, wave = tid >> 6;
    int g = lane >> 4, r = lane & 15;
    int rowbase = blockIdx.x * 64;

    const short8_t* abase = (const short8_t*)w2p;
    short8_t bfr[4][2];
#pragma unroll
    for (int sub = 0; sub < 4; sub++)
#pragma unroll
        for (int s = 0; s < 2; s++)
            bfr[sub][s] = *(const short8_t*)(c2b + (size_t)(rowbase + sub * 16 + r) * CB + s * 32 + g * 8);

    f32x4 acc2[4][4] = {};
#pragma unroll
    for (int s = 0; s < 2; s++)
#pragma unroll
        for (int mt = 0; mt < 4; mt++) {
            short8_t a = abase[(s * 16 + wave * 4 + mt) * 64 + lane];
#pragma unroll
            for (int sub = 0; sub < 4; sub++)
                acc2[sub][mt] = mfma16(a, bfr[sub][s], acc2[sub][mt]);
        }

    // stage +bias into LDS tile: lane holds 4 contiguous cols of one row
#pragma unroll
    for (int sub = 0; sub < 4; sub++)
#pragma unroll
        for (int mt = 0; mt < 4; mt++) {
            int col0 = (wave * 4 + mt) * 16 + g * 4;
            int lrow = sub * 16 + r;
            float4 bs = *(const float4*)(bias3 + col0);
            f32x4 v = acc2[sub][mt];
            float4 sv;
            sv.x = v[0] + bs.x; sv.y = v[1] + bs.y;
            sv.z = v[2] + bs.z; sv.w = v[3] + bs.w;
            *(float4*)&otile[lrow * 260 + col0] = sv;
        }
    __syncthreads();

    // coalesced residual + relu + store
    const float4* dsrc = (const float4*)(data + (size_t)rowbase * CIN);
    float4* dst = (float4*)(out + (size_t)rowbase * CIN);
#pragma unroll
    for (int p = 0; p < 16; p++) {
        int idx = p * 256 + tid;             // float4 index, 0..4095
        int row = idx >> 6, c4 = (idx & 63) << 2;
        float4 ov = *(const float4*)&otile[row * 260 + c4];
        float4 dv = dsrc[idx];
        float4 res;
        res.x = fmaxf(ov.x + dv.x, 0.f);
        res.y = fmaxf(ov.y + dv.y, 0.f);
        res.z = fmaxf(ov.z + dv.z, 0.f);
        res.w = fmaxf(ov.w + dv.w, 0.f);
        dst[idx] = res;
    }
}

extern "C" void kernel_launch(void* const* d_in, const int* in_sizes, int n_in,
                              void* d_out, int out_size, void* d_ws, size_t ws_size,
                              hipStream_t stream)
{
    const float* data = (const float*)d_in[0];
    const int* neigh  = (const int*)d_in[1];
    const float* w1 = (const float*)d_in[3];
    const float* g1 = (const float*)d_in[4];
    const float* b1 = (const float*)d_in[5];
    const float* m1 = (const float*)d_in[6];
    const float* v1 = (const float*)d_in[7];
    const float* w3 = (const float*)d_in[8];
    const float* g2 = (const float*)d_in[9];
    const float* b2 = (const float*)d_in[10];
    const float* m2 = (const float*)d_in[11];
    const float* v2 = (const float*)d_in[12];
    const float* w2 = (const float*)d_in[13];
    const float* g3 = (const float*)d_in[14];
    const float* b3 = (const float*)d_in[15];
    const float* m3 = (const float*)d_in[16];
    const float* v3 = (const float*)d_in[17];
    float* out = (float*)d_out;

    char* ws = (char*)d_ws;
    // ws layout (~25.4 MB)
    unsigned short* c1b = (unsigned short*)ws;                      // 16 MB
    unsigned short* c2b = (unsigned short*)ws;                      // alias (c1b dead after quant)
    signed char*    c1q = (signed char*)(ws + 16777216);            // 8 MB
    unsigned short* w1p = (unsigned short*)(ws + 25165824);         // 32 KB
    signed char*    w3q = (signed char*)(ws + 25198592);            // 108 KB
    unsigned short* w2p = (unsigned short*)(ws + 25309184);         // 32 KB
    float* bias1 = (float*)(ws + 25341952);
    float* bias2 = bias1 + 64;
    float* bias3 = bias1 + 128;
    unsigned* amax = (unsigned*)(ws + 25343488);                    // 16 B
    float* blockmax = (float*)(ws + 25343552);                      // 4 KB

    int n = in_sizes[0] / CIN;   // 131072

    hipLaunchKernelGGL(prep_a_kernel, dim3(130), dim3(256), 0, stream,
                       w1, w2, g1, b1, m1, v1, g2, b2, m2, v2, g3, b3, m3, v3,
                       w1p, w2p, bias1, bias2, bias3);
    hipLaunchKernelGGL(prep_bq_kernel, dim3(432), dim3(256), 0, stream,
                       w3, g2, v2, w3q, amax);
    hipLaunchKernelGGL(k1_conv1x1a, dim3(n / 128), dim3(256), 0, stream,
                       data, w1p, bias1, c1b, blockmax);
    hipLaunchKernelGGL(quant_c1_kernel, dim3(2048), dim3(256), 0, stream,
                       c1b, blockmax, c1q, amax);
    hipLaunchKernelGGL(k2_conv3x3, dim3(n / 32), dim3(64), 0, stream,
                       c1q, neigh, w3q, bias2, amax, c2b);
    hipLaunchKernelGGL(k3_conv1x1b, dim3(n / 64), dim3(256), 0, stream,
                       c2b, w2p, bias3, data, out);
}